// Round 1
// 779.552 us; speedup vs baseline: 2.4680x; 2.4680x over previous
//
#include <hip/hip_runtime.h>
#include <math.h>

#define B_ 4
#define L_ 5
#define C_ 64
#define H_ 100
#define W_ 352
#define HW_ (H_ * W_)

typedef unsigned short u16;
typedef __attribute__((ext_vector_type(8))) short short8;   // 8 x bf16 (4 VGPR)
typedef __attribute__((ext_vector_type(4))) float f32x4;    // MFMA acc

__device__ __forceinline__ float bf2f(unsigned short u) {
    return __uint_as_float(((unsigned)u) << 16);
}
__device__ __forceinline__ unsigned short f2bf(float f) {   // round-to-nearest-even
    unsigned u = __float_as_uint(f);
    unsigned r = u + 0x7fffu + ((u >> 16) & 1u);
    return (unsigned short)(r >> 16);
}

// ---------------------------------------------------------------------------
// Kernel 1: theta precompute (unchanged, verified)
// ---------------------------------------------------------------------------
__global__ void theta_kernel(const float* __restrict__ t, float* __restrict__ th) {
    int tid = threadIdx.x;
    if (tid >= B_ * L_) return;
    int b = tid / L_, l = tid % L_;
    const float* p = t + b * (L_ * L_ * 16) + l * 16;  // [b][0][l][4][4]
    float* o = th + tid * 6;
    o[0] = p[0];
    o[1] = p[1] * (100.0f / 352.0f);
    o[2] = p[3] * (2.0f / 281.6f);
    o[3] = p[4] * (352.0f / 100.0f);
    o[4] = p[5];
    o[5] = p[7] * (2.0f / 80.0f);
}

// ---------------------------------------------------------------------------
// Kernel 2: weight prep. Permute conv weights (x BN scale) into MFMA B-frag
// order: wtab[cv][kidx=tap*2+half][nc][lane][j] ; ci = half*32+8*(lane>>4)+j,
// co = nc*16+(lane&15). Also folded bias2[cv][co] = b*g + bt.
// ---------------------------------------------------------------------------
__global__ void wprep_kernel(const float* __restrict__ vw, const float* __restrict__ vg,
                             const float* __restrict__ fw, const float* __restrict__ fg,
                             const float* __restrict__ vb, const float* __restrict__ vbt,
                             const float* __restrict__ fb, const float* __restrict__ fbt,
                             u16* __restrict__ wtab, float* __restrict__ bias2) {
    int gid = blockIdx.x * 256 + threadIdx.x;
    if (gid < 2 * 36864) {
        int cv = (gid >= 36864) ? 1 : 0;
        int r = gid - cv * 36864;
        int kidx = r >> 11;          // 18 K-chunks
        int rem = r & 2047;
        int nc = rem >> 9;           // 4 co-groups
        int lane = (rem >> 3) & 63;
        int j = rem & 7;
        int tap = kidx >> 1;
        int half = kidx & 1;
        int co = nc * 16 + (lane & 15);
        int ci = half * 32 + ((lane >> 4) << 3) + j;
        const float* Wp = cv ? fw : vw;
        const float* Gp = cv ? fg : vg;
        wtab[gid] = f2bf(Wp[(co * 64 + ci) * 9 + tap] * Gp[co]);
    }
    if (gid < 128) {
        int co = gid & 63, c2 = gid >> 6;
        float g = (c2 ? fg : vg)[co];
        bias2[gid] = (c2 ? fb : vb)[co] * g + (c2 ? fbt : vbt)[co];
    }
}

// ---------------------------------------------------------------------------
// Kernel 3: warp (bilinear, zero-pad, align-corners) + max over L.
// Output layout: agg[b][p][128] bf16, ch 0-63 = vox_agg, ch 64-127 = feat_agg.
// Block = 64 pixels x 4 channel-groups; warp math once per pixel (was 64x).
// ---------------------------------------------------------------------------
__global__ __launch_bounds__(256) void warp_max_kernel(
    const float* __restrict__ x, const float* __restrict__ vox,
    const float* __restrict__ th, u16* __restrict__ agg) {
    __shared__ u16 tile[64 * 132];   // [pixel][128ch], pad 132 (2B*132=264, 8B-aligned rows)
    int tid = threadIdx.x;
    int pl = tid & 63;               // pixel lane
    int cg = tid >> 6;               // channel group 0..3
    int b = blockIdx.z;
    int p0 = blockIdx.x * 64;
    int p = p0 + pl;
    int w = p % W_, h = p / W_;
    float gx = fmaf((float)w, 2.0f / 351.0f, -1.0f);
    float gy = fmaf((float)h, 2.0f / 99.0f, -1.0f);
    int idx[L_][4];
    float wt[L_][4];
#pragma unroll
    for (int l = 0; l < L_; l++) {
        const float* t = th + (b * L_ + l) * 6;
        float sx = t[0] * gx + t[1] * gy + t[2];
        float sy = t[3] * gx + t[4] * gy + t[5];
        float px = (sx + 1.0f) * 0.5f * 351.0f;
        float py = (sy + 1.0f) * 0.5f * 99.0f;
        float x0f = floorf(px), y0f = floorf(py);
        float fx = px - x0f, fy = py - y0f;
        int x0 = (int)x0f, y0 = (int)y0f;
        int x1 = x0 + 1, y1 = y0 + 1;
        bool vx0 = (x0 >= 0) && (x0 <= W_ - 1);
        bool vx1 = (x1 >= 0) && (x1 <= W_ - 1);
        bool vy0 = (y0 >= 0) && (y0 <= H_ - 1);
        bool vy1 = (y1 >= 0) && (y1 <= H_ - 1);
        int x0c = min(max(x0, 0), W_ - 1), x1c = min(max(x1, 0), W_ - 1);
        int y0c = min(max(y0, 0), H_ - 1), y1c = min(max(y1, 0), H_ - 1);
        wt[l][0] = (1.0f - fx) * (1.0f - fy) * ((vx0 && vy0) ? 1.0f : 0.0f);
        wt[l][1] = fx * (1.0f - fy) * ((vx1 && vy0) ? 1.0f : 0.0f);
        wt[l][2] = (1.0f - fx) * fy * ((vx0 && vy1) ? 1.0f : 0.0f);
        wt[l][3] = fx * fy * ((vx1 && vy1) ? 1.0f : 0.0f);
        idx[l][0] = y0c * W_ + x0c;
        idx[l][1] = y0c * W_ + x1c;
        idx[l][2] = y1c * W_ + x0c;
        idx[l][3] = y1c * W_ + x1c;
    }
    for (int i = 0; i < 16; i++) {   // rolled loop: scalar accumulators only
        int c = cg * 16 + i;
        float fmx = -INFINITY, vmx = -INFINITY;
#pragma unroll
        for (int l = 0; l < L_; l++) {
            int off = ((b * L_ + l) * C_ + c) * HW_;
            const float* xp = x + off;
            const float* vp = vox + off;
            float s = xp[idx[l][0]] * wt[l][0] + xp[idx[l][1]] * wt[l][1] +
                      xp[idx[l][2]] * wt[l][2] + xp[idx[l][3]] * wt[l][3];
            float v = vp[idx[l][0]] * wt[l][0] + vp[idx[l][1]] * wt[l][1] +
                      vp[idx[l][2]] * wt[l][2] + vp[idx[l][3]] * wt[l][3];
            fmx = fmaxf(fmx, s);
            vmx = fmaxf(vmx, v);
        }
        tile[pl * 132 + c] = f2bf(vmx);        // vox -> ch 0-63
        tile[pl * 132 + 64 + c] = f2bf(fmx);   // feat -> ch 64-127
    }
    __syncthreads();
    // strip pad, write coalesced 16B chunks: thread (pl,cg) owns ch [cg*32, cg*32+32)
    const u16* src = tile + pl * 132 + cg * 32;
    u16* dst = agg + ((size_t)(b * HW_ + p)) * 128 + cg * 32;
#pragma unroll
    for (int k = 0; k < 4; k++) {
        unsigned long long q0 = *(const unsigned long long*)(src + k * 8);
        unsigned long long q1 = *(const unsigned long long*)(src + k * 8 + 4);
        ulonglong2 q; q.x = q0; q.y = q1;
        *(ulonglong2*)(dst + k * 8) = q;
    }
}

// ---------------------------------------------------------------------------
// Kernel 4: implicit-GEMM 3x3 conv via MFMA 16x16x32 bf16.
// grid (11 wtiles, 25 rowquads, 8 = 4b x 2conv). Wave = 1 output row segment
// (32 px) x 64 co. K = 9 taps x 64 ci, chunked 18 x 32. A direct from global
// (channel-last agg, 8 contiguous ci per lane), B from pre-permuted wtab.
// Output: vf[b][p][128] bf16 in d_out (ve ch 0-63, fe ch 64-127).
// ---------------------------------------------------------------------------
__global__ __launch_bounds__(256) void conv_mfma_kernel(
    const u16* __restrict__ agg, const u16* __restrict__ wtab,
    const float* __restrict__ bias2, u16* __restrict__ vf) {
    int tid = threadIdx.x;
    int lane = tid & 63;
    int wid = tid >> 6;
    int lm = lane & 15;            // M (A-row) / N (co) within fragment
    int lk = lane >> 4;            // K-group
    int w0 = blockIdx.x * 32;
    int h = blockIdx.y * 4 + wid;  // wave-uniform output row
    int bz = blockIdx.z;
    int b = bz & 3;
    int cv = bz >> 2;              // 0: ve=conv(vox), 1: fe=conv(feat)
    int choff = cv ? 64 : 0;
    const u16* wbase = wtab + cv * 36864 + lane * 8;
    f32x4 acc[2][4];
#pragma unroll
    for (int m = 0; m < 2; m++)
#pragma unroll
        for (int n = 0; n < 4; n++) acc[m][n] = {0.0f, 0.0f, 0.0f, 0.0f};
    size_t bbase = (size_t)b * HW_ * 128;
#pragma unroll
    for (int tap = 0; tap < 9; tap++) {
        int dh = tap / 3 - 1, dw = tap % 3 - 1;
        int hp = h + dh;
        bool hv = (hp >= 0) && (hp < H_);
        const u16* rb = agg + bbase + (size_t)(hv ? hp : 0) * (W_ * 128) + choff + 8 * lk;
        int wA = w0 + lm + dw;     // input px for m=0
        int wB = wA + 16;          // m=1
        bool v0 = hv && (wA >= 0) && (wA < W_);
        bool v1 = hv && (wB >= 0) && (wB < W_);
#pragma unroll
        for (int hf = 0; hf < 2; hf++) {
            short8 a0 = {}; short8 a1 = {};
            if (v0) a0 = *(const short8*)(rb + wA * 128 + hf * 32);
            if (v1) a1 = *(const short8*)(rb + wB * 128 + hf * 32);
            const u16* wr = wbase + (tap * 2 + hf) * 2048;
#pragma unroll
            for (int nc = 0; nc < 4; nc++) {
                short8 bfr = *(const short8*)(wr + nc * 512);
                acc[0][nc] = __builtin_amdgcn_mfma_f32_16x16x32_bf16(a0, bfr, acc[0][nc], 0, 0, 0);
                acc[1][nc] = __builtin_amdgcn_mfma_f32_16x16x32_bf16(a1, bfr, acc[1][nc], 0, 0, 0);
            }
        }
    }
    // Epilogue: D lane l holds (px = w0+m*16+lk*4+r, co = nc*16+lm)
    size_t obase = ((size_t)b * HW_ + (size_t)h * W_) * 128 + choff;
#pragma unroll
    for (int nc = 0; nc < 4; nc++) {
        float bs = bias2[cv * 64 + nc * 16 + lm];
#pragma unroll
        for (int m = 0; m < 2; m++) {
#pragma unroll
            for (int r = 0; r < 4; r++) {
                int px = w0 + m * 16 + lk * 4 + r;
                float val = fmaxf(acc[m][nc][r] + bs, 0.0f);
                vf[obase + (size_t)px * 128 + nc * 16 + lm] = f2bf(val);
            }
        }
    }
}

// ---------------------------------------------------------------------------
// Kernel 5: fused attention gate + blend. Thread = 1 pixel; 128-ch VF row is
// contiguous (16 x b128 loads). w1 reads are wave-uniform -> s_loads.
// Writes final NCHW fp32 to ws (AGG region, dead by now).
// ---------------------------------------------------------------------------
__global__ __launch_bounds__(256) void attn_fuse_kernel(
    const u16* __restrict__ vf, const float* __restrict__ x,
    const float* __restrict__ aw1, const float* __restrict__ ab1,
    const float* __restrict__ aw2, const float* __restrict__ ab2,
    float* __restrict__ outb) {
    int pix = blockIdx.x * 256 + threadIdx.x;
    int b = pix / HW_;
    int p = pix - b * HW_;
    const u16* vrow = vf + (size_t)pix * 128;
    float a[32];
#pragma unroll
    for (int k = 0; k < 32; k++) a[k] = ab1[k];
    for (int c8 = 0; c8 < 16; c8++) {
        short8 v8 = *(const short8*)(vrow + c8 * 8);
        float v[8];
#pragma unroll
        for (int j = 0; j < 8; j++) v[j] = bf2f((unsigned short)v8[j]);
        const float* w1 = aw1 + c8 * 8;
#pragma unroll
        for (int k = 0; k < 32; k++) {
#pragma unroll
            for (int j = 0; j < 8; j++)
                a[k] = fmaf(w1[k * 128 + j], v[j], a[k]);
        }
    }
    float z0 = ab2[0], z1 = ab2[1];
#pragma unroll
    for (int k = 0; k < 32; k++) {
        float a1v = fmaxf(a[k], 0.0f);
        z0 = fmaf(aw2[k], a1v, z0);
        z1 = fmaf(aw2[32 + k], a1v, z1);
    }
    float a0 = 1.0f / (1.0f + __expf(z1 - z0));
    const float* ego = x + (size_t)(b * L_) * C_ * HW_ + p;  // xb[b,0,:,p]
    float* ob = outb + (size_t)b * C_ * HW_ + p;
#pragma unroll 4
    for (int c = 0; c < 64; c++) {
        float vv = bf2f(vrow[c]);        // ve (L1-hot)
        float ff = bf2f(vrow[64 + c]);   // fe
        ob[(size_t)c * HW_] = ego[(size_t)c * HW_] + a0 * vv + (1.0f - a0) * ff;
    }
}

// ---------------------------------------------------------------------------
// Workspace (~36.2 MiB):
//   th    @ 0        (480 B)
//   wtab  @ 512      (147,456 B bf16, both convs, frag-ordered, BN-folded)
//   bias2 @ 147,968  (512 B)
//   AGG   @ 148,480  (36,044,800 B bf16 [b][p][128])  -> reused as OUT (fp32 NCHW)
// VF (ve||fe, bf16 [b][p][128]) lives in d_out; final NCHW copied back.
// ---------------------------------------------------------------------------
extern "C" void kernel_launch(void* const* d_in, const int* in_sizes, int n_in,
                              void* d_out, int out_size, void* d_ws, size_t ws_size,
                              hipStream_t stream) {
    const float* x   = (const float*)d_in[0];
    const float* vox = (const float*)d_in[1];
    // d_in[2] det_bev: dead; d_in[4] record_len: unused
    const float* pt  = (const float*)d_in[3];
    const float* vw  = (const float*)d_in[5];
    const float* vb  = (const float*)d_in[6];
    const float* vg  = (const float*)d_in[7];
    const float* vbt = (const float*)d_in[8];
    const float* fw  = (const float*)d_in[9];
    const float* fb  = (const float*)d_in[10];
    const float* fg  = (const float*)d_in[11];
    const float* fbt = (const float*)d_in[12];
    const float* aw1 = (const float*)d_in[13];
    const float* ab1 = (const float*)d_in[14];
    const float* aw2 = (const float*)d_in[15];
    const float* ab2 = (const float*)d_in[16];

    char* ws = (char*)d_ws;
    float* th    = (float*)ws;
    u16*   wtab  = (u16*)(ws + 512);
    float* bias2 = (float*)(ws + 147968);
    u16*   agg   = (u16*)(ws + 148480);
    float* outb  = (float*)(ws + 148480);   // AGG region reused after convs
    u16*   vf    = (u16*)d_out;
    const size_t VF_BYTES = (size_t)B_ * HW_ * 128 * sizeof(u16);  // 36,044,800

    theta_kernel<<<1, 32, 0, stream>>>(pt, th);
    wprep_kernel<<<288, 256, 0, stream>>>(vw, vg, fw, fg, vb, vbt, fb, fbt, wtab, bias2);

    // aggregates, channel-last
    warp_max_kernel<<<dim3(HW_ / 64, 1, B_), 256, 0, stream>>>(x, vox, th, agg);

    // both convs, one dispatch -> VF in d_out
    conv_mfma_kernel<<<dim3(W_ / 32, H_ / 4, 2 * B_), 256, 0, stream>>>(agg, wtab, bias2, vf);

    // gate + blend + ego add -> NCHW fp32 in ws
    attn_fuse_kernel<<<(B_ * HW_) / 256, 256, 0, stream>>>(vf, x, aw1, ab1, aw2, ab2, outb);

    // final 36 MB D2D copy back into d_out
    hipMemcpyAsync(d_out, outb, VF_BYTES, hipMemcpyDeviceToDevice, stream);
}